// Round 4
// baseline (192.598 us; speedup 1.0000x reference)
//
#include <hip/hip_runtime.h>
#include <hip/hip_bf16.h>

// LocalAttention B=4, L=2048, C=512, H=8, Dh=64 — round 10.
// vs round 9:
//  * attn: cross-tile software pipeline (T15): QK^T(t+1) issued after the
//    end-of-iteration barrier; softmax(t) runs one iteration behind so the
//    QK MFMA latency drains under global-prefetch issue + softmax instead of
//    stalling the wave. One barrier per tile unchanged.
//  * proj_gemm: 128Mx128N tile (2x2 waves, 64x64/wave, 4 acc tiles).
//    MFMA:ds_read 16:16 per K-step (was 8:12), staging bytes/FLOP halved,
//    B-panel re-read 4x instead of 8x.

#define BB  4
#define LL  2048
#define CC  512
#define HH  8
#define DHH 64

typedef __attribute__((ext_vector_type(8)))  short bf16x8;   // 16 B
typedef __attribute__((ext_vector_type(4)))  short bf16x4;   // 8 B
typedef __attribute__((ext_vector_type(16))) float f32x16;   // MFMA C/D
typedef __attribute__((ext_vector_type(2)))  unsigned uint2v;
typedef __attribute__((ext_vector_type(4)))  unsigned uint4v;

using us = unsigned short;

#if __has_builtin(__builtin_amdgcn_exp2f)
#define EXP2(x) __builtin_amdgcn_exp2f(x)
#else
#define EXP2(x) __expf(0.6931471805599453f * (x))
#endif

__device__ __forceinline__ int swz(int r) { return (r + (r >> 3)) & 7; }

__device__ __forceinline__ us f2bu(float x) {   // scalar fp32->bf16 (RNE)
    unsigned u = __float_as_uint(x);
    return (us)((u + 0x7FFFu + ((u >> 16) & 1u)) >> 16);
}
// HW packed fp32->bf16 (RNE), a -> low half, b -> high half
__device__ __forceinline__ unsigned pk2(float a, float b) {
    unsigned r;
    asm("v_cvt_pk_bf16_f32 %0, %1, %2" : "=v"(r) : "v"(a), "v"(b));
    return r;
}
__device__ __forceinline__ bf16x4 pk4(float a, float b, float c, float d) {
    uint2v u; u[0] = pk2(a, b); u[1] = pk2(c, d);
    return __builtin_bit_cast(bf16x4, u);
}

// ---------------------------------------------------------------------------
// transpose body: fp32 [b][c][n] -> bf16 [b][n][c] for one (b, c0, n0) tile
// ---------------------------------------------------------------------------
__device__ __forceinline__ void transpose_body(const float* __restrict__ X,
                                               us* __restrict__ Xt,
                                               int b, int c0, int n0, int t)
{
    __shared__ float T[64][65];

    const float* Xb = X + ((size_t)b * CC + c0) * LL + n0;
    #pragma unroll
    for (int i = 0; i < 4; ++i) {
        const int cl = (t >> 4) + 16 * i, nl = (t & 15) * 4;
        const float4 f = *(const float4*)(Xb + (size_t)cl * LL + nl);
        T[cl][nl + 0] = f.x; T[cl][nl + 1] = f.y;
        T[cl][nl + 2] = f.z; T[cl][nl + 3] = f.w;
    }
    __syncthreads();
    us* Ot = Xt + ((size_t)b * LL + n0) * CC + c0;
    #pragma unroll
    for (int i = 0; i < 2; ++i) {
        const int nl = (t >> 3) + 32 * i, cb = (t & 7) * 8;
        uint4v u;
        #pragma unroll
        for (int j = 0; j < 4; ++j)
            u[j] = pk2(T[cb + 2 * j][nl], T[cb + 2 * j + 1][nl]);
        *(bf16x8*)(Ot + (size_t)nl * CC + cb) = __builtin_bit_cast(bf16x8, u);
    }
}

__global__ __launch_bounds__(256) void transpose_cvt(const float* __restrict__ X,
                                                     us* __restrict__ Xt)
{
    transpose_body(X, Xt, blockIdx.z, blockIdx.y * 64, blockIdx.x * 64, threadIdx.x);
}

// fused: z = which*4 + b, which in {0:q, 1:k, 2:v}
__global__ __launch_bounds__(256) void transpose_cvt3(
    const float* __restrict__ Xq, const float* __restrict__ Xk,
    const float* __restrict__ Xv,
    us* __restrict__ X0, us* __restrict__ X1, us* __restrict__ X2)
{
    const int z = blockIdx.z, which = z >> 2, b = z & 3;
    const float* X = which == 0 ? Xq : (which == 1 ? Xk : Xv);
    us* Xt = which == 0 ? X0 : (which == 1 ? X1 : X2);
    transpose_body(X, Xt, b, blockIdx.y * 64, blockIdx.x * 64, threadIdx.x);
}

// ---------------------------------------------------------------------------
// fp32 -> bf16 for the four 512x512 weight matrices (one launch).
// ---------------------------------------------------------------------------
__global__ __launch_bounds__(256) void cvt_w4(const float* __restrict__ W0,
                                              const float* __restrict__ W1,
                                              const float* __restrict__ W2,
                                              const float* __restrict__ W3,
                                              us* __restrict__ out)
{
    const float* Ws[4] = {W0, W1, W2, W3};
    const float* W = Ws[blockIdx.y];
    us* O = out + (size_t)blockIdx.y * (CC * CC);
    const int i = (blockIdx.x * 256 + threadIdx.x) * 8;
    const float4 f0 = *(const float4*)(W + i);
    const float4 f1 = *(const float4*)(W + i + 4);
    uint4v u;
    u[0] = pk2(f0.x, f0.y); u[1] = pk2(f0.z, f0.w);
    u[2] = pk2(f1.x, f1.y); u[3] = pk2(f1.z, f1.w);
    *(bf16x8*)(O + i) = __builtin_bit_cast(bf16x8, u);
}

// ---------------------------------------------------------------------------
// GEMM core: Y[b][o][n] = sum_c W[o][c]*Xt[b][n][c] + bias[o].
// Block tile 128(M) x 128(N), BK=64, 256 thr = 4 waves in 2x2 (64x64/wave).
// Double-buffered LDS, register prefetch, 1 barrier per K-step.
// mode 0: bf16 out, per-head position-major [b][h][n][64], (acc+bias)*scale
// mode 1: bf16 out, channel-major [b][o][n]
// mode 2: fp32 out, channel-major [b][o][n]
// ---------------------------------------------------------------------------
__device__ __forceinline__ void proj_body(const us* __restrict__ Xb,   // [n][c] for batch b
                                          const us* __restrict__ Wm,   // W rows m0..m0+127
                                          const float* __restrict__ bias,
                                          float scale, void* __restrict__ Yv,
                                          int b, int n0, int m0, int t, int mode)
{
    const int lane = t & 63, wave = t >> 6;
    const int quad2 = lane >> 5, l31 = lane & 31;
    const int wr = (wave >> 1) * 64, wc = (wave & 1) * 64;

    __shared__ us As[2][128 * 64];   // [m][k] swizzled
    __shared__ us Bs[2][128 * 64];   // [n][k] swizzled
    __shared__ float biasS[128];

    f32x16 acc[2][2];
    #pragma unroll
    for (int mi = 0; mi < 2; ++mi)
        #pragma unroll
        for (int ni = 0; ni < 2; ++ni)
            #pragma unroll
            for (int e = 0; e < 16; ++e) acc[mi][ni][e] = 0.f;

    if (t < 128) biasS[t] = bias[m0 + t];

    // prologue: stage k-tile 0 into buffer 0
    #pragma unroll
    for (int i = 0; i < 4; ++i) {
        const int id = i * 256 + t, r = id >> 3, bk = id & 7;
        *(bf16x8*)(As[0] + r * 64 + ((bk ^ swz(r)) * 8)) =
            *(const bf16x8*)(Wm + (size_t)r * CC + bk * 8);
        *(bf16x8*)(Bs[0] + r * 64 + ((bk ^ swz(r)) * 8)) =
            *(const bf16x8*)(Xb + (size_t)(n0 + r) * CC + bk * 8);
    }
    __syncthreads();

    for (int it = 0; it < CC / 64; ++it) {
        const int cur = it & 1, k1 = (it + 1) * 64;

        bf16x8 apre[4], bpre[4];
        if (it + 1 < CC / 64) {
            #pragma unroll
            for (int i = 0; i < 4; ++i) {
                const int id = i * 256 + t, r = id >> 3, bk = id & 7;
                apre[i] = *(const bf16x8*)(Wm + (size_t)r * CC + k1 + bk * 8);
                bpre[i] = *(const bf16x8*)(Xb + (size_t)(n0 + r) * CC + k1 + bk * 8);
            }
        }

        __builtin_amdgcn_s_setprio(1);
        #pragma unroll
        for (int ks = 0; ks < 4; ++ks) {
            const int bk = quad2 + 2 * ks;
            const int ra0 = wr + l31, ra1 = ra0 + 32;
            const int rb0 = wc + l31, rb1 = rb0 + 32;
            const bf16x8 af0 = *(const bf16x8*)(As[cur] + ra0 * 64 + ((bk ^ swz(ra0)) * 8));
            const bf16x8 af1 = *(const bf16x8*)(As[cur] + ra1 * 64 + ((bk ^ swz(ra1)) * 8));
            const bf16x8 bf0 = *(const bf16x8*)(Bs[cur] + rb0 * 64 + ((bk ^ swz(rb0)) * 8));
            const bf16x8 bf1 = *(const bf16x8*)(Bs[cur] + rb1 * 64 + ((bk ^ swz(rb1)) * 8));
            acc[0][0] = __builtin_amdgcn_mfma_f32_32x32x16_bf16(af0, bf0, acc[0][0], 0, 0, 0);
            acc[0][1] = __builtin_amdgcn_mfma_f32_32x32x16_bf16(af0, bf1, acc[0][1], 0, 0, 0);
            acc[1][0] = __builtin_amdgcn_mfma_f32_32x32x16_bf16(af1, bf0, acc[1][0], 0, 0, 0);
            acc[1][1] = __builtin_amdgcn_mfma_f32_32x32x16_bf16(af1, bf1, acc[1][1], 0, 0, 0);
        }
        __builtin_amdgcn_s_setprio(0);

        if (it + 1 < CC / 64) {
            #pragma unroll
            for (int i = 0; i < 4; ++i) {
                const int id = i * 256 + t, r = id >> 3, bk = id & 7;
                *(bf16x8*)(As[1 - cur] + r * 64 + ((bk ^ swz(r)) * 8)) = apre[i];
                *(bf16x8*)(Bs[1 - cur] + r * 64 + ((bk ^ swz(r)) * 8)) = bpre[i];
            }
        }
        __syncthreads();
    }

    #pragma unroll
    for (int mi = 0; mi < 2; ++mi)
        #pragma unroll
        for (int ni = 0; ni < 2; ++ni) {
            const int nloc = wc + ni * 32 + l31;
            if (mode == 0) {
                us* Y = (us*)Yv;
                #pragma unroll
                for (int rg2 = 0; rg2 < 4; ++rg2) {
                    const int rbase = wr + mi * 32 + 8 * rg2 + 4 * quad2;
                    float v0 = (acc[mi][ni][rg2 * 4 + 0] + biasS[rbase + 0]) * scale;
                    float v1 = (acc[mi][ni][rg2 * 4 + 1] + biasS[rbase + 1]) * scale;
                    float v2 = (acc[mi][ni][rg2 * 4 + 2] + biasS[rbase + 2]) * scale;
                    float v3 = (acc[mi][ni][rg2 * 4 + 3] + biasS[rbase + 3]) * scale;
                    const int mg = m0 + rbase;
                    const int h = mg >> 6, d = mg & 63;
                    *(bf16x4*)(Y + (((size_t)(b * HH + h) * LL) + n0 + nloc) * DHH + d) =
                        pk4(v0, v1, v2, v3);
                }
            } else {
                #pragma unroll
                for (int reg = 0; reg < 16; ++reg) {
                    const int row = (reg & 3) + 8 * (reg >> 2) + 4 * quad2;
                    const int mloc = wr + mi * 32 + row;
                    const float v = (acc[mi][ni][reg] + biasS[mloc]) * scale;
                    const size_t addr = ((size_t)b * CC + m0 + mloc) * LL + n0 + nloc;
                    if (mode == 1) ((us*)Yv)[addr] = f2bu(v);
                    else           ((float*)Yv)[addr] = v;
                }
            }
        }
}

template <int MODE>
__global__ __launch_bounds__(256, 2) void proj_gemm(const us* __restrict__ Xt,
                                                    const us* __restrict__ Wb,
                                                    const float* __restrict__ bias,
                                                    float scale,
                                                    void* __restrict__ Yv)
{
    const int b = blockIdx.z, n0 = blockIdx.x * 128, m0 = blockIdx.y * 128;
    proj_body(Xt + (size_t)b * LL * CC, Wb + (size_t)m0 * CC, bias, scale, Yv,
              b, n0, m0, threadIdx.x, MODE);
}

// fused q/k/v projection: z = which*4 + b
__global__ __launch_bounds__(256, 2) void proj_gemm3(
    const us* __restrict__ X0, const us* __restrict__ X1, const us* __restrict__ X2,
    const us* __restrict__ Wb4,
    const float* __restrict__ bq, const float* __restrict__ bk,
    const float* __restrict__ bv, float scale_q,
    us* __restrict__ qh, us* __restrict__ kh, us* __restrict__ vh)
{
    const int z = blockIdx.z, which = z >> 2, b = z & 3;
    const int n0 = blockIdx.x * 128, m0 = blockIdx.y * 128;
    const us* Xt = which == 0 ? X0 : (which == 1 ? X1 : X2);
    const us* Wb = Wb4 + (size_t)which * (CC * CC);
    const float* bias = which == 0 ? bq : (which == 1 ? bk : bv);
    const float scale = which == 0 ? scale_q : 1.0f;
    us* Yv = which == 0 ? qh : (which == 1 ? kh : vh);
    const int mode = (which == 2) ? 1 : 0;
    proj_body(Xt + (size_t)b * LL * CC, Wb + (size_t)m0 * CC, bias, scale,
              (void*)Yv, b, n0, m0, threadIdx.x, mode);
}

// ---------------------------------------------------------------------------
// Flash attention. Block = 256 thr (4 waves), each wave owns 32 queries.
// S^T[64 n][32 q] = K^T Q  (q pre-scaled by 0.125*log2e), exp2-direct
// softmax, P in registers (cvt_pk + permlane32_swap -> PV B-fragments).
// Cross-tile pipeline: QK^T(t+1) is issued after the end-of-iteration
// barrier; softmax runs one tile behind, so QK MFMA latency drains under
// the next iteration's global prefetch + softmax VALU.
// ---------------------------------------------------------------------------
__global__ __launch_bounds__(256, 2) void attn_fwd(
    const us* __restrict__ Qh,     // [b][h][l][64], pre-scaled
    const us* __restrict__ Kh,     // [b][h][l][64]
    const us* __restrict__ Vh,     // [b][512][l] channel-major
    const float* __restrict__ mask,// [b][1][L]
    us* __restrict__ ctx)          // [b][l][512]
{
    const int bh = blockIdx.x;     // 0..31
    const int b = bh >> 3, h = bh & 7;
    const int qb = blockIdx.y;     // 0..15
    const int t = threadIdx.x, lane = t & 63, wave = t >> 6;
    const int quad2 = lane >> 5, l31 = lane & 31;
    const int qg = qb * 128 + wave * 32;     // wave's query base
    const int NT = LL / 64;

    __shared__ us Ks[2][64 * 64];  // [n][d] swizzled, double-buffered
    __shared__ us Vs[2][64 * 64];  // [d][n] swizzled
    __shared__ unsigned long long mwS[32];

    const float* mb = mask + (size_t)b * LL;
    #pragma unroll
    for (int i = 0; i < 8; ++i) {            // precompute all mask ballots
        const int tile = wave * 8 + i;
        const unsigned long long bal = __ballot(mb[tile * 64 + lane] > 0.5f);
        if (lane == 0) mwS[tile] = bal;
    }

    // Q fragments (register-resident)
    const us* Qbase = Qh + (size_t)bh * LL * DHH;
    bf16x8 qf[4];
    #pragma unroll
    for (int ks = 0; ks < 4; ++ks)
        qf[ks] = *(const bf16x8*)(Qbase + (size_t)(qg + l31) * DHH + ks * 16 + quad2 * 8);

    f32x16 of[2];
    #pragma unroll
    for (int mt = 0; mt < 2; ++mt)
        #pragma unroll
        for (int e = 0; e < 16; ++e) of[mt][e] = 0.f;
    float l_run = 0.f;

    const us* Kbase = Kh + (size_t)bh * LL * DHH;
    const us* Vbase = Vh + ((size_t)b * CC + h * DHH) * LL;

    // stage tile 0 into buffer 0
    #pragma unroll
    for (int i = 0; i < 2; ++i) {
        const int id = i * 256 + t;
        const int r = id >> 3, bk = id & 7;
        *(bf16x8*)(Ks[0] + r * 64 + ((bk ^ swz(r)) * 8)) =
            *(const bf16x8*)(Kbase + (size_t)r * DHH + bk * 8);
        *(bf16x8*)(Vs[0] + r * 64 + ((bk ^ swz(r)) * 8)) =
            *(const bf16x8*)(Vbase + (size_t)r * LL + bk * 8);
    }
    __syncthreads();

    // QK^T for tile 0
    f32x16 sf[2];
    #pragma unroll
    for (int mt = 0; mt < 2; ++mt)
        #pragma unroll
        for (int e = 0; e < 16; ++e) sf[mt][e] = 0.f;
    __builtin_amdgcn_s_setprio(1);
    #pragma unroll
    for (int ks = 0; ks < 4; ++ks) {
        const int bk = quad2 + 2 * ks;
        #pragma unroll
        for (int mt = 0; mt < 2; ++mt) {
            const int r = mt * 32 + l31;
            const bf16x8 af = *(const bf16x8*)(Ks[0] + r * 64 + ((bk ^ swz(r)) * 8));
            sf[mt] = __builtin_amdgcn_mfma_f32_32x32x16_bf16(af, qf[ks], sf[mt], 0, 0, 0);
        }
    }
    __builtin_amdgcn_s_setprio(0);

    for (int it = 0; it < NT; ++it) {
        const int cur = it & 1;

        // prefetch next K/V tile into registers (issue early)
        bf16x8 kpre[2], vpre[2];
        if (it + 1 < NT) {
            const int n1 = (it + 1) * 64;
            #pragma unroll
            for (int i = 0; i < 2; ++i) {
                const int id = i * 256 + t;
                const int r = id >> 3, bk = id & 7;
                kpre[i] = *(const bf16x8*)(Kbase + (size_t)(n1 + r) * DHH + bk * 8);
                vpre[i] = *(const bf16x8*)(Vbase + (size_t)r * LL + n1 + bk * 8);
            }
        }

        // exp2-direct softmax on sf (tile it)
        const unsigned long long mw = mwS[it];
        const bool masked = (mw != 0xFFFFFFFFFFFFFFFFull);
        float ps = 0.f;
        bf16x8 pfrag[4];
        #pragma unroll
        for (int mt = 0; mt < 2; ++mt) {
            float p[16];
            #pragma unroll
            for (int e = 0; e < 16; ++e) p[e] = EXP2(sf[mt][e]);
            if (masked) {
                #pragma unroll
                for (int e = 0; e < 16; ++e) {
                    const int row = 32 * mt + (e & 3) + 8 * (e >> 2) + 4 * quad2;
                    p[e] = ((mw >> row) & 1ull) ? p[e] : 0.f;
                }
            }
            const float s0 = (p[0] + p[1]) + (p[2] + p[3]);
            const float s1 = (p[4] + p[5]) + (p[6] + p[7]);
            const float s2 = (p[8] + p[9]) + (p[10] + p[11]);
            const float s3 = (p[12] + p[13]) + (p[14] + p[15]);
            ps += (s0 + s1) + (s2 + s3);
            // v_permlane32_swap_b32 vdst, vsrc:
            //   new_vdst = {lo: old_vdst.lo, hi: old_vsrc.lo}
            //   new_vsrc = {lo: old_vdst.hi, hi: old_vsrc.hi}
            // => vdst = low-n pair word (w0/w1), vsrc = +4 pair word (w2/w3).
            #pragma unroll
            for (int g = 0; g < 2; ++g) {
                unsigned w0 = pk2(p[8 * g + 0], p[8 * g + 1]);
                unsigned w1 = pk2(p[8 * g + 2], p[8 * g + 3]);
                unsigned w2 = pk2(p[8 * g + 4], p[8 * g + 5]);
                unsigned w3 = pk2(p[8 * g + 6], p[8 * g + 7]);
                asm("v_permlane32_swap_b32 %0, %1" : "+v"(w0), "+v"(w2));
                asm("v_permlane32_swap_b32 %0, %1" : "+v"(w1), "+v"(w3));
                uint4v u; u[0] = w0; u[1] = w1; u[2] = w2; u[3] = w3;
                pfrag[2 * mt + g] = __builtin_bit_cast(bf16x8, u);
            }
        }
        ps += __shfl_xor(ps, 32, 64);
        l_run += ps;

        // O^T += V P^T (tile it)
        __builtin_amdgcn_s_setprio(1);
        #pragma unroll
        for (int ks = 0; ks < 4; ++ks) {
            const int bk = quad2 + 2 * ks;
            #pragma unroll
            for (int mt = 0; mt < 2; ++mt) {
                const int r = mt * 32 + l31;
                const bf16x8 vf = *(const bf16x8*)(Vs[cur] + r * 64 + ((bk ^ swz(r)) * 8));
                of[mt] = __builtin_amdgcn_mfma_f32_32x32x16_bf16(vf, pfrag[ks], of[mt], 0, 0, 0);
            }
        }
        __builtin_amdgcn_s_setprio(0);

        // write prefetched tile it+1 to the alternate buffer
        if (it + 1 < NT) {
            #pragma unroll
            for (int i = 0; i < 2; ++i) {
                const int id = i * 256 + t;
                const int r = id >> 3, bk = id & 7;
                *(bf16x8*)(Ks[1 - cur] + r * 64 + ((bk ^ swz(r)) * 8)) = kpre[i];
                *(bf16x8*)(Vs[1 - cur] + r * 64 + ((bk ^ swz(r)) * 8)) = vpre[i];
            }
        }
        __syncthreads();

        // QK^T for tile it+1 (pipelined: consumed by next iteration's softmax)
        if (it + 1 < NT) {
            #pragma unroll
            for (int mt = 0; mt < 2; ++mt)
                #pragma unroll
                for (int e = 0; e < 16; ++e) sf[mt][e] = 0.f;
            __builtin_amdgcn_s_setprio(1);
            #pragma unroll
            for (int ks = 0; ks < 4; ++ks) {
                const int bk = quad2 + 2 * ks;
                #pragma unroll
                for (int mt = 0; mt < 2; ++mt) {
                    const int r = mt * 32 + l31;
                    const bf16x8 af = *(const bf16x8*)(Ks[1 - cur] + r * 64 + ((bk ^ swz(r)) * 8));
                    sf[mt] = __builtin_amdgcn_mfma_f32_32x32x16_bf16(af, qf[ks], sf[mt], 0, 0, 0);
                }
            }
            __builtin_amdgcn_s_setprio(0);
        }
    }

    // epilogue: ctx[b][q][h*64+d] = O^T[d][q] / l_run
    us* Cb = ctx + (size_t)b * LL * CC;
    const float inv = 1.0f / l_run;
    const int q = qg + l31;
    #pragma unroll
    for (int mt = 0; mt < 2; ++mt)
        #pragma unroll
        for (int rg2 = 0; rg2 < 4; ++rg2) {
            const int d = 32 * mt + 8 * rg2 + 4 * quad2;
            *(bf16x4*)(Cb + (size_t)q * CC + h * DHH + d) =
                pk4(of[mt][rg2 * 4 + 0] * inv, of[mt][rg2 * 4 + 1] * inv,
                    of[mt][rg2 * 4 + 2] * inv, of[mt][rg2 * 4 + 3] * inv);
        }
}

// ---------------------------------------------------------------------------
extern "C" void kernel_launch(void* const* d_in, const int* in_sizes, int n_in,
                              void* d_out, int out_size, void* d_ws, size_t ws_size,
                              hipStream_t stream)
{
    const float* q    = (const float*)d_in[0];
    const float* k    = (const float*)d_in[1];
    const float* v    = (const float*)d_in[2];
    const float* mask = (const float*)d_in[3];
    const float* Wq   = (const float*)d_in[4];
    const float* bq   = (const float*)d_in[5];
    const float* Wk   = (const float*)d_in[6];
    const float* bk   = (const float*)d_in[7];
    const float* Wv   = (const float*)d_in[8];
    const float* bv   = (const float*)d_in[9];
    const float* Wout = (const float*)d_in[10];
    const float* bout = (const float*)d_in[11];

    const size_t TSZ  = (size_t)BB * CC * LL;    // 4,194,304 elements (8 MB)
    const size_t WSZ  = (size_t)4 * CC * CC;     // 1,048,576 elements (2 MB)
    const float SCALE_Q = 0.125f * 1.4426950408889634f;  // softmax scale * log2e

    const dim3 tb(256), gb(256);

    if (ws_size >= (6 * TSZ + WSZ) * sizeof(us)) {
        // fused path: 5 launches
        us* X0  = (us*)d_ws;
        us* X1  = X0 + TSZ;
        us* X2  = X1 + TSZ;
        us* qh  = X2 + TSZ;
        us* kh  = qh + TSZ;
        us* vh  = kh + TSZ;
        us* Wb  = vh + TSZ;
        us* ctx = X0;                            // X0 dead after proj3

        cvt_w4<<<dim3(CC * CC / 2048, 4), tb, 0, stream>>>(Wq, Wk, Wv, Wout, Wb);
        transpose_cvt3<<<dim3(LL / 64, CC / 64, 12), tb, 0, stream>>>(q, k, v, X0, X1, X2);
        proj_gemm3<<<dim3(LL / 128, CC / 128, 12), gb, 0, stream>>>(
            X0, X1, X2, Wb, bq, bk, bv, SCALE_Q, qh, kh, vh);
        attn_fwd<<<dim3(HH * BB, LL / 128), tb, 0, stream>>>(qh, kh, vh, mask, ctx);
        proj_gemm<2><<<dim3(LL / 128, CC / 128, BB), gb, 0, stream>>>(
            ctx, Wb + 3 * (size_t)CC * CC, bout, 1.0f, d_out);
    } else {
        // fallback: sequential path reusing one Xt buffer
        us* Xt  = (us*)d_ws;
        us* qh  = Xt + TSZ;
        us* kh  = qh + TSZ;
        us* vh  = kh + TSZ;
        us* Wb  = vh + TSZ;
        us* ctx = Xt;

        const dim3 tg(LL / 64, CC / 64, BB), gg(LL / 128, CC / 128, BB);

        cvt_w4<<<dim3(CC * CC / 2048, 4), tb, 0, stream>>>(Wq, Wk, Wv, Wout, Wb);
        transpose_cvt<<<tg, tb, 0, stream>>>(q, Xt);
        proj_gemm<0><<<gg, gb, 0, stream>>>(Xt, Wb + 0 * (size_t)CC * CC, bq, SCALE_Q, (void*)qh);
        transpose_cvt<<<tg, tb, 0, stream>>>(k, Xt);
        proj_gemm<0><<<gg, gb, 0, stream>>>(Xt, Wb + 1 * (size_t)CC * CC, bk, 1.0f, (void*)kh);
        transpose_cvt<<<tg, tb, 0, stream>>>(v, Xt);
        proj_gemm<1><<<gg, gb, 0, stream>>>(Xt, Wb + 2 * (size_t)CC * CC, bv, 1.0f, (void*)vh);
        attn_fwd<<<dim3(HH * BB, LL / 128), tb, 0, stream>>>(qh, kh, vh, mask, ctx);
        proj_gemm<2><<<gg, gb, 0, stream>>>(ctx, Wb + 3 * (size_t)CC * CC, bout, 1.0f, d_out);
    }
}